// Round 4
// baseline (226.276 us; speedup 1.0000x reference)
//
#include <hip/hip_runtime.h>
#include <math.h>

#define NP 50000
#define CH 64
#define KMAX 64
#define KNN 16
#define NB 25
#define PTS (NP / NB)            // 2000
#define EPSF 1e-16f
#define NTILES (NP / 16)         // 3125 (16-node tiles for qkv)
#define ATILES (NP / 4)          // 12500 (4-node tiles for attn)
#define TPW 4
#define L2E 1.4426950408889634f
#define LN2 0.6931471805599453f

typedef __attribute__((ext_vector_type(8))) short short8;
typedef __attribute__((ext_vector_type(4))) float float4v;
typedef __attribute__((ext_vector_type(4))) unsigned int uint4v;
typedef __attribute__((ext_vector_type(2))) unsigned int uint2v;
typedef __attribute__((ext_vector_type(4))) unsigned short ushort4v;

__device__ __forceinline__ ushort f2b(float f) {
  unsigned u = __float_as_uint(f);
  unsigned r = (u + 0x7FFFu + ((u >> 16) & 1u)) >> 16;
  return (ushort)r;
}
__device__ __forceinline__ float b2f(ushort h) {
  return __uint_as_float(((unsigned)h) << 16);
}

// ws layout (bytes):
//   qbf  : 3 * NP * CH * 2   (bf16, log2e-scaled Q)
//   kvp  : 3 * NP * CH * 4   (packed dword: K_s bf16 hi | V bf16 lo)
//   x_bf : NP * CH * 2
//   wpack: 36864 ushort (A-frag layout; Q,K pre-scaled by log2e)
//   pool : NB * CH fp32
#define QBF_BYTES   ((size_t)3 * NP * CH * 2)
#define KVP_BYTES   ((size_t)3 * NP * CH * 4)
#define XBF_BYTES   ((size_t)NP * CH * 2)
#define WPACK_ELEMS (9 * 4 * 2 * 64 * 8)
#define XV (NP * CH / 4)

// ---------------------------------------------------------------------------
// Kernel 0: prep = pool (blocks 0..24) + x->bf16 + W pack (A-frag layout).
// ---------------------------------------------------------------------------
__global__ __launch_bounds__(256) void prep_kernel(
    const float* __restrict__ x,
    const float* __restrict__ Wv,
    const float* __restrict__ Wq,
    const float* __restrict__ Wk,
    ushort* __restrict__ x_bf,
    ushort* __restrict__ wpack,
    float* __restrict__ pool) {
  const int tid = threadIdx.x;
  const int bid = blockIdx.x;
  __shared__ float red[4][CH];

  if (bid < NB) {
    const int lane = tid & 63;
    const int wave = tid >> 6;
    const float* xb = x + (size_t)bid * PTS * CH;
    float m0 = -INFINITY, m1 = -INFINITY, m2 = -INFINITY, m3 = -INFINITY;
    for (int r = wave * 4; r < PTS; r += 16) {
      m0 = fmaxf(m0, xb[(size_t)(r + 0) * CH + lane]);
      m1 = fmaxf(m1, xb[(size_t)(r + 1) * CH + lane]);
      m2 = fmaxf(m2, xb[(size_t)(r + 2) * CH + lane]);
      m3 = fmaxf(m3, xb[(size_t)(r + 3) * CH + lane]);
    }
    red[wave][lane] = fmaxf(fmaxf(m0, m1), fmaxf(m2, m3));
    __syncthreads();
    if (wave == 0) {
      pool[bid * CH + lane] = fmaxf(fmaxf(red[0][lane], red[1][lane]),
                                    fmaxf(red[2][lane], red[3][lane]));
    }
  } else {
    const int gid = (bid - NB) * 256 + tid;
    if (gid < XV) {
      const float4* xv = (const float4*)x;
      float4 v = xv[gid];
      ushort4v o;
      o[0] = f2b(v.x); o[1] = f2b(v.y); o[2] = f2b(v.z); o[3] = f2b(v.w);
      *(ushort4v*)(x_bf + (size_t)gid * 4) = o;
    } else {
      int pid = gid - XV;
      if (pid < WPACK_ELEMS) {
        int j     = pid & 7;
        int lane  = (pid >> 3) & 63;
        int kstep = (pid >> 9) & 1;
        int mtile = (pid >> 10) & 3;
        int mat   = pid >> 12;
        const float* W;
        int d;
        float scale;
        if (mat < 3)      { W = Wq; d = mat;     scale = L2E; }
        else if (mat < 6) { W = Wk; d = mat - 3; scale = L2E; }
        else              { W = Wv; d = mat - 6; scale = 1.f; }
        int oc = mtile * 16 + (lane & 15);
        int ic = kstep * 32 + ((lane >> 4) & 3) * 8 + j;
        wpack[pid] = f2b(W[d * CH * CH + ic * CH + oc] * scale);
      }
    }
  }
}

// ---------------------------------------------------------------------------
// Kernel 1: projections via MFMA. y = dd; each wave computes Q (planar bf16)
// and packed KV for its tiles with 24 resident A-frags (B loaded once/tile).
// D lane: node=lane&15, oc=mt*16+(lane>>4)*4+reg.
// ---------------------------------------------------------------------------
__global__ __launch_bounds__(256) void qkv_mfma(
    const ushort* __restrict__ x_bf,
    const ushort* __restrict__ wpack,
    ushort* __restrict__ qbf,
    unsigned int* __restrict__ kvp) {
  const int lane = threadIdx.x;
  const int wave = threadIdx.y;
  const int dd   = blockIdx.y;
  const int kbase = (lane >> 4) * 8;
  const int tile0 = (blockIdx.x * 4 + wave) * TPW;

  short8 afQ[4][2], afK[4][2], afV[4][2];
#pragma unroll
  for (int mt = 0; mt < 4; ++mt)
#pragma unroll
    for (int ks = 0; ks < 2; ++ks) {
      afQ[mt][ks] = *(const short8*)(wpack +
          ((((size_t)dd * 4 + mt) * 2 + ks) * 64 + lane) * 8);
      afK[mt][ks] = *(const short8*)(wpack +
          ((((size_t)(3 + dd) * 4 + mt) * 2 + ks) * 64 + lane) * 8);
      afV[mt][ks] = *(const short8*)(wpack +
          ((((size_t)(6 + dd) * 4 + mt) * 2 + ks) * 64 + lane) * 8);
    }

  ushort* outQ = qbf + (size_t)dd * NP * CH;
  unsigned int* outKV = kvp + (size_t)dd * NP * CH;

#pragma unroll
  for (int t = 0; t < TPW; ++t) {
    int tile = tile0 + t;
    if (tile >= NTILES) break;
    int myNode = tile * 16 + (lane & 15);
    const ushort* xr = x_bf + (size_t)myNode * CH;
    short8 b0 = *(const short8*)(xr + kbase);
    short8 b1 = *(const short8*)(xr + 32 + kbase);
#pragma unroll
    for (int mt = 0; mt < 4; ++mt) {
      float4v aQ = {0.f, 0.f, 0.f, 0.f};
      aQ = __builtin_amdgcn_mfma_f32_16x16x32_bf16(afQ[mt][0], b0, aQ, 0, 0, 0);
      aQ = __builtin_amdgcn_mfma_f32_16x16x32_bf16(afQ[mt][1], b1, aQ, 0, 0, 0);
      int oc = mt * 16 + (lane >> 4) * 4;
      uint2v oq;
      oq[0] = (unsigned)f2b(aQ[0]) | ((unsigned)f2b(aQ[1]) << 16);
      oq[1] = (unsigned)f2b(aQ[2]) | ((unsigned)f2b(aQ[3]) << 16);
      *(uint2v*)(outQ + (size_t)myNode * CH + oc) = oq;
    }
#pragma unroll
    for (int mt = 0; mt < 4; ++mt) {
      float4v aK = {0.f, 0.f, 0.f, 0.f};
      float4v aV = {0.f, 0.f, 0.f, 0.f};
      aK = __builtin_amdgcn_mfma_f32_16x16x32_bf16(afK[mt][0], b0, aK, 0, 0, 0);
      aK = __builtin_amdgcn_mfma_f32_16x16x32_bf16(afK[mt][1], b1, aK, 0, 0, 0);
      aV = __builtin_amdgcn_mfma_f32_16x16x32_bf16(afV[mt][0], b0, aV, 0, 0, 0);
      aV = __builtin_amdgcn_mfma_f32_16x16x32_bf16(afV[mt][1], b1, aV, 0, 0, 0);
      int oc = mt * 16 + (lane >> 4) * 4;
      uint4v o;
#pragma unroll
      for (int i = 0; i < 4; ++i)
        o[i] = ((unsigned)f2b(aK[i]) << 16) | (unsigned)f2b(aV[i]);
      *(uint4v*)(outKV + (size_t)myNode * CH + oc) = o;
    }
  }
}

// ---------------------------------------------------------------------------
// Kernel 2: fused attention. Block = (64,3): 4 nodes, wave dd handles one
// dilation (16 edges); lane: node group g=lane>>4, channels (lane&15)*4..+3.
// LDS strides padded (260 / 68 floats) -> conflict-free group reads.
// XCD swizzle: blockIdx%8 selects a contiguous 1/8 node slice for L2 reuse.
// Branch-max combine via LDS, then pool + residual, single store.
// ---------------------------------------------------------------------------
__global__ __launch_bounds__(192) void attn_kernel(
    const float* __restrict__ x,
    const float* __restrict__ pos,
    const float* __restrict__ Wp,
    const float* __restrict__ bp,
    const int*   __restrict__ edge_src,
    const ushort* __restrict__ qbf,
    const unsigned int* __restrict__ kvp,
    const float* __restrict__ pool,
    float* __restrict__ out) {
  const int bx  = blockIdx.x;
  const int xcd = bx & 7;
  const int kk  = bx >> 3;
  const int base = (ATILES * xcd) >> 3;
  const int cnt  = ((ATILES * (xcd + 1)) >> 3) - base;
  if (kk >= cnt) return;                    // whole-block uniform
  const int node0 = (base + kk) * 4;

  const int tid = threadIdx.y * 64 + threadIdx.x;
  __shared__ float sEdge[4 * 260];          // [nl][p] {relx,rely,relz,rowOfs}
  __shared__ float sRes[2 * 4 * 68];        // [dd-1][nl][ch]

  for (int r = tid; r < 4 * KMAX; r += 192) {
    int nl = r >> 6, p = r & 63;
    int nd = node0 + nl;
    int j = edge_src[(size_t)nd * KMAX + p];
    float4v w;
    w[0] = pos[nd * 3 + 0] - pos[j * 3 + 0];
    w[1] = pos[nd * 3 + 1] - pos[j * 3 + 1];
    w[2] = pos[nd * 3 + 2] - pos[j * 3 + 2];
    w[3] = __int_as_float(j << 8);          // byte offset of packed-KV row
    *(float4v*)&sEdge[nl * 260 + p * 4] = w;
  }
  __syncthreads();

  const int dd   = threadIdx.y;             // wave-uniform dilation
  const int lane = threadIdx.x;
  const int g    = lane >> 4;
  const int cl   = lane & 15;
  const int node = node0 + g;
  const float* sMy = &sEdge[g * 260];
  const unsigned clOfs = (unsigned)(cl << 4);

  float4v q, bq, wp0, wp1, wp2;
  {
    ushort4v qh = *(const ushort4v*)(qbf + ((size_t)dd * NP + node) * CH + cl * 4);
#pragma unroll
    for (int i = 0; i < 4; ++i) q[i] = b2f(qh[i]);
    const float* WpD = Wp + dd * 192;
    wp0 = *(const float4v*)(WpD + 0 * 64 + cl * 4) * L2E;
    wp1 = *(const float4v*)(WpD + 1 * 64 + cl * 4) * L2E;
    wp2 = *(const float4v*)(WpD + 2 * 64 + cl * 4) * L2E;
    float4v bpv = *(const float4v*)(bp + dd * 64 + cl * 4);
    bq = q + bpv * L2E;
  }
  const char* KVb = (const char*)(kvp + (size_t)dd * NP * CH);

  float4v s    = {0.f, 0.f, 0.f, 0.f};
  float4v accv = {0.f, 0.f, 0.f, 0.f};
  float4v acct = {0.f, 0.f, 0.f, 0.f};
#pragma unroll
  for (int e = 0; e < KNN; ++e) {
    const int p = e << dd;
    float4v w = *(const float4v*)(sMy + p * 4);
    uint4v u = *(const uint4v*)(KVb + (__float_as_uint(w[3]) + clOfs));
    float4v kf, vf, wgt;
#pragma unroll
    for (int i = 0; i < 4; ++i) kf[i] = __uint_as_float(u[i] & 0xFFFF0000u);
#pragma unroll
    for (int i = 0; i < 4; ++i) vf[i] = __uint_as_float(u[i] << 16);
    float4v t = bq + w[0] * wp0 + w[1] * wp1 + w[2] * wp2;  // q_s + delta_s
    float4v a = t - kf;
#pragma unroll
    for (int i = 0; i < 4; ++i) wgt[i] = __builtin_amdgcn_exp2f(a[i]);
    s    += wgt;
    accv += wgt * vf;
    acct += wgt * t;
  }
  float4v r;
#pragma unroll
  for (int i = 0; i < 4; ++i) {
    float accd = acct[i] - q[i] * s[i];     // sum w * delta_s
    r[i] = (accv[i] + LN2 * accd) * __builtin_amdgcn_rcpf(s[i] + EPSF);
  }

  if (dd > 0)
    *(float4v*)&sRes[((dd - 1) * 4 + g) * 68 + cl * 4] = r;
  __syncthreads();
  if (dd == 0) {
    float4v r1 = *(const float4v*)&sRes[(0 * 4 + g) * 68 + cl * 4];
    float4v r2 = *(const float4v*)&sRes[(1 * 4 + g) * 68 + cl * 4];
    const int b = node / PTS;
    float4v pv = *(const float4v*)(pool + b * CH + cl * 4);
    float4v xv = *(const float4v*)(x + (size_t)node * CH + cl * 4);
    float4v res;
#pragma unroll
    for (int i = 0; i < 4; ++i)
      res[i] = fmaxf(fmaxf(fmaxf(r[i], r1[i]), r2[i]), pv[i]) + xv[i];
    *(float4v*)(out + (size_t)node * CH + cl * 4) = res;
  }
}

// ---------------------------------------------------------------------------
extern "C" void kernel_launch(void* const* d_in, const int* in_sizes, int n_in,
                              void* d_out, int out_size, void* d_ws, size_t ws_size,
                              hipStream_t stream) {
  const float* x    = (const float*)d_in[0];
  const float* pos  = (const float*)d_in[1];
  const float* Wv   = (const float*)d_in[2];
  const float* Wq   = (const float*)d_in[3];
  const float* Wk   = (const float*)d_in[4];
  const float* Wp   = (const float*)d_in[5];
  const float* bp   = (const float*)d_in[6];
  const int*   ei   = (const int*)d_in[7];
  float* out = (float*)d_out;

  char* wsb = (char*)d_ws;
  ushort* qbf   = (ushort*)wsb;
  unsigned int* kvp = (unsigned int*)(wsb + QBF_BYTES);
  ushort* x_bf  = (ushort*)(wsb + QBF_BYTES + KVP_BYTES);
  ushort* wpack = (ushort*)(wsb + QBF_BYTES + KVP_BYTES + XBF_BYTES);
  float*  pool  = (float*)(wsb + QBF_BYTES + KVP_BYTES + XBF_BYTES +
                           (size_t)WPACK_ELEMS * 2);

  // 0) pool + convert + pack
  {
    int convBlocks = (XV + WPACK_ELEMS + 255) / 256;
    dim3 grid(NB + convBlocks);
    hipLaunchKernelGGL(prep_kernel, grid, dim3(256), 0, stream,
                       x, Wv, Wq, Wk, x_bf, wpack, pool);
  }
  // 1) Q + packed KV via MFMA (3 dilation slices)
  {
    dim3 grid((NTILES + 4 * TPW - 1) / (4 * TPW), 3);
    dim3 block(64, 4);
    hipLaunchKernelGGL(qkv_mfma, grid, block, 0, stream, x_bf, wpack, qbf, kvp);
  }
  // 2) fused attention + combine
  {
    dim3 grid(8 * ((ATILES + 7) / 8));
    dim3 block(64, 3);
    hipLaunchKernelGGL(attn_kernel, grid, block, 0, stream,
                       x, pos, Wp, bp, ei, qbf, kvp, pool, out);
  }
}

// Round 5
// 218.157 us; speedup vs baseline: 1.0372x; 1.0372x over previous
//
#include <hip/hip_runtime.h>
#include <math.h>

#define NP 50000
#define CH 64
#define KMAX 64
#define KNN 16
#define NB 25
#define PTS (NP / NB)            // 2000
#define EPSF 1e-16f
#define NTILES (NP / 16)         // 3125 (16-node tiles for qkv)
#define ATILES (NP / 4)          // 12500 (4-node tiles for attn)
#define L2E 1.4426950408889634f
#define LN2 0.6931471805599453f

typedef __attribute__((ext_vector_type(8))) short short8;
typedef __attribute__((ext_vector_type(4))) float float4v;
typedef __attribute__((ext_vector_type(4))) unsigned int uint4v;
typedef __attribute__((ext_vector_type(2))) unsigned int uint2v;
typedef __attribute__((ext_vector_type(4))) unsigned short ushort4v;

__device__ __forceinline__ ushort f2b(float f) {
  unsigned u = __float_as_uint(f);
  unsigned r = (u + 0x7FFFu + ((u >> 16) & 1u)) >> 16;
  return (ushort)r;
}
__device__ __forceinline__ float b2f(ushort h) {
  return __uint_as_float(((unsigned)h) << 16);
}

// ws layout (bytes):
//   qbf  : 3 * NP * CH * 2   (bf16, log2e-scaled Q)
//   kvp  : 3 * NP * CH * 4   (packed dword: K_s bf16 hi | V bf16 lo)
//   x_bf : NP * CH * 2
//   wpack: 36864 ushort (A-frag layout; Q,K pre-scaled by log2e)
//   pool : NB * CH fp32
#define QBF_BYTES   ((size_t)3 * NP * CH * 2)
#define KVP_BYTES   ((size_t)3 * NP * CH * 4)
#define XBF_BYTES   ((size_t)NP * CH * 2)
#define WPACK_ELEMS (9 * 4 * 2 * 64 * 8)
#define XV (NP * CH / 4)

// ---------------------------------------------------------------------------
// Kernel 0: prep = pool (blocks 0..24) + x->bf16 + W pack (A-frag layout).
// ---------------------------------------------------------------------------
__global__ __launch_bounds__(256) void prep_kernel(
    const float* __restrict__ x,
    const float* __restrict__ Wv,
    const float* __restrict__ Wq,
    const float* __restrict__ Wk,
    ushort* __restrict__ x_bf,
    ushort* __restrict__ wpack,
    float* __restrict__ pool) {
  const int tid = threadIdx.x;
  const int bid = blockIdx.x;
  __shared__ float red[4][CH];

  if (bid < NB) {
    const int lane = tid & 63;
    const int wave = tid >> 6;
    const float* xb = x + (size_t)bid * PTS * CH;
    float m0 = -INFINITY, m1 = -INFINITY, m2 = -INFINITY, m3 = -INFINITY;
    for (int r = wave * 4; r < PTS; r += 16) {
      m0 = fmaxf(m0, xb[(size_t)(r + 0) * CH + lane]);
      m1 = fmaxf(m1, xb[(size_t)(r + 1) * CH + lane]);
      m2 = fmaxf(m2, xb[(size_t)(r + 2) * CH + lane]);
      m3 = fmaxf(m3, xb[(size_t)(r + 3) * CH + lane]);
    }
    red[wave][lane] = fmaxf(fmaxf(m0, m1), fmaxf(m2, m3));
    __syncthreads();
    if (wave == 0) {
      pool[bid * CH + lane] = fmaxf(fmaxf(red[0][lane], red[1][lane]),
                                    fmaxf(red[2][lane], red[3][lane]));
    }
  } else {
    const int gid = (bid - NB) * 256 + tid;
    if (gid < XV) {
      const float4* xv = (const float4*)x;
      float4 v = xv[gid];
      ushort4v o;
      o[0] = f2b(v.x); o[1] = f2b(v.y); o[2] = f2b(v.z); o[3] = f2b(v.w);
      *(ushort4v*)(x_bf + (size_t)gid * 4) = o;
    } else {
      int pid = gid - XV;
      if (pid < WPACK_ELEMS) {
        int j     = pid & 7;
        int lane  = (pid >> 3) & 63;
        int kstep = (pid >> 9) & 1;
        int mtile = (pid >> 10) & 3;
        int mat   = pid >> 12;
        const float* W;
        int d;
        float scale;
        if (mat < 3)      { W = Wq; d = mat;     scale = L2E; }
        else if (mat < 6) { W = Wk; d = mat - 3; scale = L2E; }
        else              { W = Wv; d = mat - 6; scale = 1.f; }
        int oc = mtile * 16 + (lane & 15);
        int ic = kstep * 32 + ((lane >> 4) & 3) * 8 + j;
        wpack[pid] = f2b(W[d * CH * CH + ic * CH + oc] * scale);
      }
    }
  }
}

// ---------------------------------------------------------------------------
// Kernel 1: projections via MFMA 16x16x32 bf16 (A=W^T, B=x^T). 1 tile/wave.
// grid.y: 0..2 = Q_dd (8 A-frags), 3..5 = KV_dd packed (16 A-frags).
// D lane: node=lane&15, oc=mt*16+(lane>>4)*4+reg.
// ---------------------------------------------------------------------------
__global__ __launch_bounds__(256) void qkv_mfma(
    const ushort* __restrict__ x_bf,
    const ushort* __restrict__ wpack,
    ushort* __restrict__ qbf,
    unsigned int* __restrict__ kvp) {
  const int lane = threadIdx.x;
  const int tile = blockIdx.x * 4 + threadIdx.y;
  if (tile >= NTILES) return;
  const int y = blockIdx.y;
  const int kbase = (lane >> 4) * 8;
  const int myNode = tile * 16 + (lane & 15);
  const ushort* xr = x_bf + (size_t)myNode * CH;
  short8 b0 = *(const short8*)(xr + kbase);
  short8 b1 = *(const short8*)(xr + 32 + kbase);

  if (y < 3) {                             // ---- Q slice ----
    const int dd = y;
    ushort* outQ = qbf + (size_t)dd * NP * CH;
#pragma unroll
    for (int mt = 0; mt < 4; ++mt) {
      short8 a0 = *(const short8*)(wpack +
          ((((size_t)dd * 4 + mt) * 2 + 0) * 64 + lane) * 8);
      short8 a1 = *(const short8*)(wpack +
          ((((size_t)dd * 4 + mt) * 2 + 1) * 64 + lane) * 8);
      float4v acc = {0.f, 0.f, 0.f, 0.f};
      acc = __builtin_amdgcn_mfma_f32_16x16x32_bf16(a0, b0, acc, 0, 0, 0);
      acc = __builtin_amdgcn_mfma_f32_16x16x32_bf16(a1, b1, acc, 0, 0, 0);
      int oc = mt * 16 + (lane >> 4) * 4;
      uint2v o;
      o[0] = (unsigned)f2b(acc[0]) | ((unsigned)f2b(acc[1]) << 16);
      o[1] = (unsigned)f2b(acc[2]) | ((unsigned)f2b(acc[3]) << 16);
      *(uint2v*)(outQ + (size_t)myNode * CH + oc) = o;
    }
  } else {                                 // ---- KV packed slice ----
    const int dd = y - 3;
    unsigned int* outKV = kvp + (size_t)dd * NP * CH;
#pragma unroll
    for (int mt = 0; mt < 4; ++mt) {
      short8 k0 = *(const short8*)(wpack +
          ((((size_t)(3 + dd) * 4 + mt) * 2 + 0) * 64 + lane) * 8);
      short8 k1 = *(const short8*)(wpack +
          ((((size_t)(3 + dd) * 4 + mt) * 2 + 1) * 64 + lane) * 8);
      short8 v0 = *(const short8*)(wpack +
          ((((size_t)(6 + dd) * 4 + mt) * 2 + 0) * 64 + lane) * 8);
      short8 v1 = *(const short8*)(wpack +
          ((((size_t)(6 + dd) * 4 + mt) * 2 + 1) * 64 + lane) * 8);
      float4v aK = {0.f, 0.f, 0.f, 0.f};
      float4v aV = {0.f, 0.f, 0.f, 0.f};
      aK = __builtin_amdgcn_mfma_f32_16x16x32_bf16(k0, b0, aK, 0, 0, 0);
      aK = __builtin_amdgcn_mfma_f32_16x16x32_bf16(k1, b1, aK, 0, 0, 0);
      aV = __builtin_amdgcn_mfma_f32_16x16x32_bf16(v0, b0, aV, 0, 0, 0);
      aV = __builtin_amdgcn_mfma_f32_16x16x32_bf16(v1, b1, aV, 0, 0, 0);
      int oc = mt * 16 + (lane >> 4) * 4;
      uint4v o;
#pragma unroll
      for (int i = 0; i < 4; ++i)
        o[i] = ((unsigned)f2b(aK[i]) << 16) | (unsigned)f2b(aV[i]);
      *(uint4v*)(outKV + (size_t)myNode * CH + oc) = o;
    }
  }
}

// ---------------------------------------------------------------------------
// Kernel 2: fused attention. Block = (64,6): 4 nodes; wave wy = (dd, half),
// each handling 8 of a dilation's 16 edges. lane: node group g=lane>>4,
// channels (lane&15)*4..+3. Partials merged via conflict-free padded LDS.
// XCD swizzle keeps each XCD's gathers in ~3 clouds (L2-resident KV).
// ---------------------------------------------------------------------------
__global__ __launch_bounds__(384, 6) void attn_kernel(
    const float* __restrict__ x,
    const float* __restrict__ pos,
    const float* __restrict__ Wp,
    const float* __restrict__ bp,
    const int*   __restrict__ edge_src,
    const ushort* __restrict__ qbf,
    const unsigned int* __restrict__ kvp,
    const float* __restrict__ pool,
    float* __restrict__ out) {
  const int bx  = blockIdx.x;
  const int xcd = bx & 7;
  const int kk  = bx >> 3;
  const int base = (ATILES * xcd) >> 3;
  const int cnt  = ((ATILES * (xcd + 1)) >> 3) - base;
  if (kk >= cnt) return;                    // whole-block uniform
  const int node0 = (base + kk) * 4;

  const int wy   = threadIdx.y;             // 0..5
  const int dd   = wy % 3;                  // wave-uniform dilation
  const int half = wy / 3;                  // 0 or 1 (edge half)
  const int tid  = wy * 64 + threadIdx.x;

  __shared__ float sEdge[4 * 260];          // [nl][p] {relx,rely,relz,rowOfs}
  __shared__ float sPartS[3 * 4 * 68];      // [dd][nl][ch] partial s
  __shared__ float sPartA[3 * 4 * 68];      // [dd][nl][ch] partial accv
  __shared__ float sRes[2 * 4 * 68];        // [dd-1][nl][ch] branch result

  if (tid < 256) {
    int nl = tid >> 6, p = tid & 63;
    int nd = node0 + nl;
    int j = edge_src[(size_t)nd * KMAX + p];
    float4v w;
    w[0] = pos[nd * 3 + 0] - pos[j * 3 + 0];
    w[1] = pos[nd * 3 + 1] - pos[j * 3 + 1];
    w[2] = pos[nd * 3 + 2] - pos[j * 3 + 2];
    w[3] = __int_as_float(j << 8);          // byte offset of packed-KV row
    *(float4v*)&sEdge[nl * 260 + p * 4] = w;
  }
  __syncthreads();

  const int lane = threadIdx.x;
  const int g    = lane >> 4;
  const int cl   = lane & 15;
  const int node = node0 + g;
  const float* sMy = &sEdge[g * 260];
  const unsigned clOfs = (unsigned)(cl << 4);

  float4v bq, wp0, wp1, wp2;
  {
    ushort4v qh = *(const ushort4v*)(qbf + ((size_t)dd * NP + node) * CH + cl * 4);
    const float* WpD = Wp + dd * 192;
    wp0 = *(const float4v*)(WpD + 0 * 64 + cl * 4) * L2E;
    wp1 = *(const float4v*)(WpD + 1 * 64 + cl * 4) * L2E;
    wp2 = *(const float4v*)(WpD + 2 * 64 + cl * 4) * L2E;
    float4v bpv = *(const float4v*)(bp + dd * 64 + cl * 4);
#pragma unroll
    for (int i = 0; i < 4; ++i) bq[i] = b2f(qh[i]) + bpv[i] * L2E;
  }
  const char* KVb = (const char*)(kvp + (size_t)dd * NP * CH);

  float4v s    = {0.f, 0.f, 0.f, 0.f};
  float4v accv = {0.f, 0.f, 0.f, 0.f};
#pragma unroll
  for (int e = 0; e < 8; ++e) {
    const int p = (half * 8 + e) << dd;
    float4v w = *(const float4v*)(sMy + p * 4);
    uint4v u = *(const uint4v*)(KVb + (__float_as_uint(w[3]) + clOfs));
    float4v kf, vf, wgt;
#pragma unroll
    for (int i = 0; i < 4; ++i) kf[i] = __uint_as_float(u[i] & 0xFFFF0000u);
#pragma unroll
    for (int i = 0; i < 4; ++i) vf[i] = __uint_as_float(u[i] << 16);
    float4v t = bq + w[0] * wp0 + w[1] * wp1 + w[2] * wp2;  // q_s + delta_s
    float4v a = t - kf;
#pragma unroll
    for (int i = 0; i < 4; ++i) wgt[i] = __builtin_amdgcn_exp2f(a[i]);
    s += wgt;
    float4v vt;
#pragma unroll
    for (int i = 0; i < 4; ++i) vt[i] = fmaf(LN2, t[i], vf[i]);  // v + ln2*t
    accv += wgt * vt;
  }

  if (half == 1) {
    *(float4v*)&sPartS[(dd * 4 + g) * 68 + cl * 4] = s;
    *(float4v*)&sPartA[(dd * 4 + g) * 68 + cl * 4] = accv;
  }
  __syncthreads();

  float4v r;
  if (half == 0) {
    float4v s2 = *(const float4v*)&sPartS[(dd * 4 + g) * 68 + cl * 4];
    float4v a2 = *(const float4v*)&sPartA[(dd * 4 + g) * 68 + cl * 4];
    s += s2;
    accv += a2;
    float4v bpv = *(const float4v*)(bp + dd * 64 + cl * 4);
#pragma unroll
    for (int i = 0; i < 4; ++i) {
      float q = (bq[i] - bpv[i] * L2E) * LN2;    // undo log2e scaling
      r[i] = accv[i] * __builtin_amdgcn_rcpf(s[i] + EPSF) - q;
    }
    if (dd > 0)
      *(float4v*)&sRes[((dd - 1) * 4 + g) * 68 + cl * 4] = r;
  }
  __syncthreads();

  if (wy == 0) {                            // dd==0, half==0: final combine
    float4v r1 = *(const float4v*)&sRes[(0 * 4 + g) * 68 + cl * 4];
    float4v r2 = *(const float4v*)&sRes[(1 * 4 + g) * 68 + cl * 4];
    const int b = node / PTS;
    float4v pv = *(const float4v*)(pool + b * CH + cl * 4);
    float4v xv = *(const float4v*)(x + (size_t)node * CH + cl * 4);
    float4v res;
#pragma unroll
    for (int i = 0; i < 4; ++i)
      res[i] = fmaxf(fmaxf(fmaxf(r[i], r1[i]), r2[i]), pv[i]) + xv[i];
    *(float4v*)(out + (size_t)node * CH + cl * 4) = res;
  }
}

// ---------------------------------------------------------------------------
extern "C" void kernel_launch(void* const* d_in, const int* in_sizes, int n_in,
                              void* d_out, int out_size, void* d_ws, size_t ws_size,
                              hipStream_t stream) {
  const float* x    = (const float*)d_in[0];
  const float* pos  = (const float*)d_in[1];
  const float* Wv   = (const float*)d_in[2];
  const float* Wq   = (const float*)d_in[3];
  const float* Wk   = (const float*)d_in[4];
  const float* Wp   = (const float*)d_in[5];
  const float* bp   = (const float*)d_in[6];
  const int*   ei   = (const int*)d_in[7];
  float* out = (float*)d_out;

  char* wsb = (char*)d_ws;
  ushort* qbf   = (ushort*)wsb;
  unsigned int* kvp = (unsigned int*)(wsb + QBF_BYTES);
  ushort* x_bf  = (ushort*)(wsb + QBF_BYTES + KVP_BYTES);
  ushort* wpack = (ushort*)(wsb + QBF_BYTES + KVP_BYTES + XBF_BYTES);
  float*  pool  = (float*)(wsb + QBF_BYTES + KVP_BYTES + XBF_BYTES +
                           (size_t)WPACK_ELEMS * 2);

  // 0) pool + convert + pack
  {
    int convBlocks = (XV + WPACK_ELEMS + 255) / 256;
    dim3 grid(NB + convBlocks);
    hipLaunchKernelGGL(prep_kernel, grid, dim3(256), 0, stream,
                       x, Wv, Wq, Wk, x_bf, wpack, pool);
  }
  // 1) Q + packed KV via MFMA (6 slices, 1 tile/wave)
  {
    dim3 grid((NTILES + 3) / 4, 6);
    dim3 block(64, 4);
    hipLaunchKernelGGL(qkv_mfma, grid, block, 0, stream, x_bf, wpack, qbf, kvp);
  }
  // 2) fused attention + combine
  {
    dim3 grid(8 * ((ATILES + 7) / 8));
    dim3 block(64, 6);
    hipLaunchKernelGGL(attn_kernel, grid, block, 0, stream,
                       x, pos, Wp, bp, ei, qbf, kvp, pool, out);
  }
}

// Round 6
// 186.738 us; speedup vs baseline: 1.2117x; 1.1683x over previous
//
#include <hip/hip_runtime.h>
#include <math.h>

#define NP 50000
#define CH 64
#define KMAX 64
#define KNN 16
#define NB 25
#define PTS (NP / NB)            // 2000
#define EPSF 1e-16f
#define NTILES (NP / 16)         // 3125 (16-node tiles for qkv)
#define ATILES (NP / 4)          // 12500 (4-node tiles for attn)
#define L2E 1.4426950408889634f
#define LN2 0.6931471805599453f
#define PPB 8                    // pool partials per cloud
#define PROWS (PTS / PPB)        // 250

typedef __attribute__((ext_vector_type(8))) short short8;
typedef __attribute__((ext_vector_type(4))) float float4v;
typedef __attribute__((ext_vector_type(4))) unsigned int uint4v;
typedef __attribute__((ext_vector_type(2))) unsigned int uint2v;
typedef __attribute__((ext_vector_type(4))) unsigned short ushort4v;

__device__ __forceinline__ ushort f2b(float f) {
  unsigned u = __float_as_uint(f);
  unsigned r = (u + 0x7FFFu + ((u >> 16) & 1u)) >> 16;
  return (ushort)r;
}
__device__ __forceinline__ float b2f(ushort h) {
  return __uint_as_float(((unsigned)h) << 16);
}

// ws layout (bytes):
//   qbf  : 3 * NP * CH * 2   (bf16, log2e-scaled Q)
//   kvp  : 3 * NP * CH * 4   (packed dword: K_s bf16 hi | V bf16 lo)
//   x_bf : NP * CH * 2
//   wpack: 36864 ushort (A-frag layout; Q,K pre-scaled by log2e)
//   poolP: NB * PPB * CH fp32 (per-cloud pool partials)
#define QBF_BYTES   ((size_t)3 * NP * CH * 2)
#define KVP_BYTES   ((size_t)3 * NP * CH * 4)
#define XBF_BYTES   ((size_t)NP * CH * 2)
#define WPACK_ELEMS (9 * 4 * 2 * 64 * 8)
#define XV (NP * CH / 4)

// ---------------------------------------------------------------------------
// Kernel 0: prep = pool partials (blocks 0..NB*PPB-1) + x->bf16 + W pack.
// ---------------------------------------------------------------------------
__global__ __launch_bounds__(256) void prep_kernel(
    const float* __restrict__ x,
    const float* __restrict__ Wv,
    const float* __restrict__ Wq,
    const float* __restrict__ Wk,
    ushort* __restrict__ x_bf,
    ushort* __restrict__ wpack,
    float* __restrict__ poolP) {
  const int tid = threadIdx.x;
  const int bid = blockIdx.x;
  __shared__ float red[4][CH];

  if (bid < NB * PPB) {                 // ---- pool partial path ----
    const int lane = tid & 63;
    const int wave = tid >> 6;
    const int cloud = bid >> 3;
    const int part  = bid & 7;
    const float* xb = x + ((size_t)cloud * PTS + part * PROWS) * CH;
    float m0 = -INFINITY, m1 = -INFINITY;
    for (int r = wave * 2; r < PROWS; r += 8) {
      m0 = fmaxf(m0, xb[(size_t)(r + 0) * CH + lane]);
      m1 = fmaxf(m1, xb[(size_t)(r + 1) * CH + lane]);
    }
    red[wave][lane] = fmaxf(m0, m1);
    __syncthreads();
    if (wave == 0) {
      poolP[(size_t)bid * CH + lane] = fmaxf(fmaxf(red[0][lane], red[1][lane]),
                                             fmaxf(red[2][lane], red[3][lane]));
    }
  } else {                              // ---- convert / pack path ----
    const int gid = (bid - NB * PPB) * 256 + tid;
    if (gid < XV) {
      const float4* xv = (const float4*)x;
      float4 v = xv[gid];
      ushort4v o;
      o[0] = f2b(v.x); o[1] = f2b(v.y); o[2] = f2b(v.z); o[3] = f2b(v.w);
      *(ushort4v*)(x_bf + (size_t)gid * 4) = o;
    } else {
      int pid = gid - XV;
      if (pid < WPACK_ELEMS) {
        int j     = pid & 7;
        int lane  = (pid >> 3) & 63;
        int kstep = (pid >> 9) & 1;
        int mtile = (pid >> 10) & 3;
        int mat   = pid >> 12;
        const float* W;
        int d;
        float scale;
        if (mat < 3)      { W = Wq; d = mat;     scale = L2E; }
        else if (mat < 6) { W = Wk; d = mat - 3; scale = L2E; }
        else              { W = Wv; d = mat - 6; scale = 1.f; }
        int oc = mtile * 16 + (lane & 15);
        int ic = kstep * 32 + ((lane >> 4) & 3) * 8 + j;
        wpack[pid] = f2b(W[d * CH * CH + ic * CH + oc] * scale);
      }
    }
  }
}

// ---------------------------------------------------------------------------
// Kernel 1: projections via MFMA 16x16x32 bf16 (A=W^T, B=x^T). 1 tile/wave.
// grid.y: 0..2 = Q_dd (8 A-frags), 3..5 = KV_dd packed (16 A-frags).
// D lane: node=lane&15, oc=mt*16+(lane>>4)*4+reg.
// ---------------------------------------------------------------------------
__global__ __launch_bounds__(256) void qkv_mfma(
    const ushort* __restrict__ x_bf,
    const ushort* __restrict__ wpack,
    ushort* __restrict__ qbf,
    unsigned int* __restrict__ kvp) {
  const int lane = threadIdx.x;
  const int tile = blockIdx.x * 4 + threadIdx.y;
  if (tile >= NTILES) return;
  const int y = blockIdx.y;
  const int kbase = (lane >> 4) * 8;
  const int myNode = tile * 16 + (lane & 15);
  const ushort* xr = x_bf + (size_t)myNode * CH;
  short8 b0 = *(const short8*)(xr + kbase);
  short8 b1 = *(const short8*)(xr + 32 + kbase);

  if (y < 3) {                             // ---- Q slice ----
    const int dd = y;
    ushort* outQ = qbf + (size_t)dd * NP * CH;
#pragma unroll
    for (int mt = 0; mt < 4; ++mt) {
      short8 a0 = *(const short8*)(wpack +
          ((((size_t)dd * 4 + mt) * 2 + 0) * 64 + lane) * 8);
      short8 a1 = *(const short8*)(wpack +
          ((((size_t)dd * 4 + mt) * 2 + 1) * 64 + lane) * 8);
      float4v acc = {0.f, 0.f, 0.f, 0.f};
      acc = __builtin_amdgcn_mfma_f32_16x16x32_bf16(a0, b0, acc, 0, 0, 0);
      acc = __builtin_amdgcn_mfma_f32_16x16x32_bf16(a1, b1, acc, 0, 0, 0);
      int oc = mt * 16 + (lane >> 4) * 4;
      uint2v o;
      o[0] = (unsigned)f2b(acc[0]) | ((unsigned)f2b(acc[1]) << 16);
      o[1] = (unsigned)f2b(acc[2]) | ((unsigned)f2b(acc[3]) << 16);
      *(uint2v*)(outQ + (size_t)myNode * CH + oc) = o;
    }
  } else {                                 // ---- KV packed slice ----
    const int dd = y - 3;
    unsigned int* outKV = kvp + (size_t)dd * NP * CH;
#pragma unroll
    for (int mt = 0; mt < 4; ++mt) {
      short8 k0 = *(const short8*)(wpack +
          ((((size_t)(3 + dd) * 4 + mt) * 2 + 0) * 64 + lane) * 8);
      short8 k1 = *(const short8*)(wpack +
          ((((size_t)(3 + dd) * 4 + mt) * 2 + 1) * 64 + lane) * 8);
      short8 v0 = *(const short8*)(wpack +
          ((((size_t)(6 + dd) * 4 + mt) * 2 + 0) * 64 + lane) * 8);
      short8 v1 = *(const short8*)(wpack +
          ((((size_t)(6 + dd) * 4 + mt) * 2 + 1) * 64 + lane) * 8);
      float4v aK = {0.f, 0.f, 0.f, 0.f};
      float4v aV = {0.f, 0.f, 0.f, 0.f};
      aK = __builtin_amdgcn_mfma_f32_16x16x32_bf16(k0, b0, aK, 0, 0, 0);
      aK = __builtin_amdgcn_mfma_f32_16x16x32_bf16(k1, b1, aK, 0, 0, 0);
      aV = __builtin_amdgcn_mfma_f32_16x16x32_bf16(v0, b0, aV, 0, 0, 0);
      aV = __builtin_amdgcn_mfma_f32_16x16x32_bf16(v1, b1, aV, 0, 0, 0);
      int oc = mt * 16 + (lane >> 4) * 4;
      uint4v o;
#pragma unroll
      for (int i = 0; i < 4; ++i)
        o[i] = ((unsigned)f2b(aK[i]) << 16) | (unsigned)f2b(aV[i]);
      *(uint4v*)(outKV + (size_t)myNode * CH + oc) = o;
    }
  }
}

// ---------------------------------------------------------------------------
// Kernel 2: fused attention. Block = (64,6): 4 nodes; wave wy = (dd, half),
// each handling 8 of a dilation's 16 edges. Partials published as
// {s, P = accv - q*s} -> single combine wave, only TWO barriers total.
// XCD swizzle keeps each XCD's gathers in ~3 clouds (L2-resident KV).
// ---------------------------------------------------------------------------
__global__ __launch_bounds__(384, 6) void attn_kernel(
    const float* __restrict__ x,
    const float* __restrict__ pos,
    const float* __restrict__ Wp,
    const float* __restrict__ bp,
    const int*   __restrict__ edge_src,
    const ushort* __restrict__ qbf,
    const unsigned int* __restrict__ kvp,
    const float* __restrict__ poolP,
    float* __restrict__ out) {
  const int bx  = blockIdx.x;
  const int xcd = bx & 7;
  const int kk  = bx >> 3;
  const int base = (ATILES * xcd) >> 3;
  const int cnt  = ((ATILES * (xcd + 1)) >> 3) - base;
  if (kk >= cnt) return;                    // whole-block uniform
  const int node0 = (base + kk) * 4;

  const int wy   = threadIdx.y;             // 0..5
  const int dd   = wy % 3;                  // wave-uniform dilation
  const int half = wy / 3;                  // 0 or 1 (edge half)
  const int tid  = wy * 64 + threadIdx.x;

  __shared__ float sEdge[4 * 260];          // [nl][p] {relx,rely,relz,rowOfs}
  __shared__ float sS[6 * 4 * 68];          // [wy][nl][ch] partial s
  __shared__ float sP[6 * 4 * 68];          // [wy][nl][ch] partial accv-q*s

  if (tid < 256) {
    int nl = tid >> 6, p = tid & 63;
    int nd = node0 + nl;
    int j = edge_src[(size_t)nd * KMAX + p];
    float4v w;
    w[0] = pos[nd * 3 + 0] - pos[j * 3 + 0];
    w[1] = pos[nd * 3 + 1] - pos[j * 3 + 1];
    w[2] = pos[nd * 3 + 2] - pos[j * 3 + 2];
    w[3] = __int_as_float(j << 8);          // byte offset of packed-KV row
    *(float4v*)&sEdge[nl * 260 + p * 4] = w;
  }
  __syncthreads();

  const int lane = threadIdx.x;
  const int g    = lane >> 4;
  const int cl   = lane & 15;
  const int node = node0 + g;
  const unsigned clOfs = (unsigned)(cl << 4);

  float4v bq, qorig, wp0, wp1, wp2;
  {
    ushort4v qh = *(const ushort4v*)(qbf + ((size_t)dd * NP + node) * CH + cl * 4);
    const float* WpD = Wp + dd * 192;
    wp0 = *(const float4v*)(WpD + 0 * 64 + cl * 4) * L2E;
    wp1 = *(const float4v*)(WpD + 1 * 64 + cl * 4) * L2E;
    wp2 = *(const float4v*)(WpD + 2 * 64 + cl * 4) * L2E;
    float4v bpv = *(const float4v*)(bp + dd * 64 + cl * 4);
    float4v qf;
#pragma unroll
    for (int i = 0; i < 4; ++i) qf[i] = b2f(qh[i]);
    bq = qf + bpv * L2E;
    qorig = qf * LN2;
  }
  const char* KVb = (const char*)(kvp + (size_t)dd * NP * CH);

  // strength-reduced LDS walk: start at edge (half*8)<<dd, step (1<<dd)
  const float* ep = &sEdge[g * 260] + (((half * 8) << dd) * 4);
  const int estep = (1 << dd) * 4;          // floats per edge step

  float4v s    = {0.f, 0.f, 0.f, 0.f};
  float4v accv = {0.f, 0.f, 0.f, 0.f};
#pragma unroll
  for (int e = 0; e < 8; ++e) {
    float4v w = *(const float4v*)ep;
    ep += estep;
    uint4v u = *(const uint4v*)(KVb + (__float_as_uint(w[3]) + clOfs));
    float4v kf, vf, wgt;
#pragma unroll
    for (int i = 0; i < 4; ++i) kf[i] = __uint_as_float(u[i] & 0xFFFF0000u);
#pragma unroll
    for (int i = 0; i < 4; ++i) vf[i] = __uint_as_float(u[i] << 16);
    float4v t = bq + w[0] * wp0 + w[1] * wp1 + w[2] * wp2;  // q_s + delta_s
    float4v a = t - kf;
#pragma unroll
    for (int i = 0; i < 4; ++i) wgt[i] = __builtin_amdgcn_exp2f(a[i]);
    s += wgt;
    accv += wgt * (vf + t * LN2);           // w * (v + ln2*t)
  }

  // publish partials: P = accv - q*s  (q uniform across halves)
  float4v P = accv - qorig * s;
  *(float4v*)&sS[(wy * 4 + g) * 68 + cl * 4] = s;
  *(float4v*)&sP[(wy * 4 + g) * 68 + cl * 4] = P;
  __syncthreads();

  if (wy == 0) {                            // single combine wave
    float4v res;
#pragma unroll
    for (int d2 = 0; d2 < 3; ++d2) {
      float4v s0 = *(const float4v*)&sS[((d2    ) * 4 + g) * 68 + cl * 4];
      float4v s1 = *(const float4v*)&sS[((d2 + 3) * 4 + g) * 68 + cl * 4];
      float4v p0 = *(const float4v*)&sP[((d2    ) * 4 + g) * 68 + cl * 4];
      float4v p1 = *(const float4v*)&sP[((d2 + 3) * 4 + g) * 68 + cl * 4];
      float4v st = s0 + s1;
      float4v pt = p0 + p1;
      float4v r;
#pragma unroll
      for (int i = 0; i < 4; ++i)
        r[i] = pt[i] * __builtin_amdgcn_rcpf(st[i] + EPSF);
      if (d2 == 0) res = r;
      else {
#pragma unroll
        for (int i = 0; i < 4; ++i) res[i] = fmaxf(res[i], r[i]);
      }
    }
    const int b = node / PTS;
    const float* pp = poolP + (size_t)(b * PPB) * CH + cl * 4;
    float4v pv = *(const float4v*)pp;
#pragma unroll
    for (int q2 = 1; q2 < PPB; ++q2) {
      float4v t2 = *(const float4v*)(pp + (size_t)q2 * CH);
#pragma unroll
      for (int i = 0; i < 4; ++i) pv[i] = fmaxf(pv[i], t2[i]);
    }
    float4v xv = *(const float4v*)(x + (size_t)node * CH + cl * 4);
#pragma unroll
    for (int i = 0; i < 4; ++i) res[i] = fmaxf(res[i], pv[i]) + xv[i];
    *(float4v*)(out + (size_t)node * CH + cl * 4) = res;
  }
}

// ---------------------------------------------------------------------------
extern "C" void kernel_launch(void* const* d_in, const int* in_sizes, int n_in,
                              void* d_out, int out_size, void* d_ws, size_t ws_size,
                              hipStream_t stream) {
  const float* x    = (const float*)d_in[0];
  const float* pos  = (const float*)d_in[1];
  const float* Wv   = (const float*)d_in[2];
  const float* Wq   = (const float*)d_in[3];
  const float* Wk   = (const float*)d_in[4];
  const float* Wp   = (const float*)d_in[5];
  const float* bp   = (const float*)d_in[6];
  const int*   ei   = (const int*)d_in[7];
  float* out = (float*)d_out;

  char* wsb = (char*)d_ws;
  ushort* qbf   = (ushort*)wsb;
  unsigned int* kvp = (unsigned int*)(wsb + QBF_BYTES);
  ushort* x_bf  = (ushort*)(wsb + QBF_BYTES + KVP_BYTES);
  ushort* wpack = (ushort*)(wsb + QBF_BYTES + KVP_BYTES + XBF_BYTES);
  float*  poolP = (float*)(wsb + QBF_BYTES + KVP_BYTES + XBF_BYTES +
                           (size_t)WPACK_ELEMS * 2);

  // 0) pool partials + convert + pack
  {
    int convBlocks = (XV + WPACK_ELEMS + 255) / 256;
    dim3 grid(NB * PPB + convBlocks);
    hipLaunchKernelGGL(prep_kernel, grid, dim3(256), 0, stream,
                       x, Wv, Wq, Wk, x_bf, wpack, poolP);
  }
  // 1) Q + packed KV via MFMA (6 slices, 1 tile/wave)
  {
    dim3 grid((NTILES + 3) / 4, 6);
    dim3 block(64, 4);
    hipLaunchKernelGGL(qkv_mfma, grid, block, 0, stream, x_bf, wpack, qbf, kvp);
  }
  // 2) fused attention + combine
  {
    dim3 grid(8 * ((ATILES + 7) / 8));
    dim3 block(64, 6);
    hipLaunchKernelGGL(attn_kernel, grid, block, 0, stream,
                       x, pos, Wp, bp, ei, qbf, kvp, poolP, out);
  }
}